// Round 18
// baseline (2061.881 us; speedup 1.0000x reference)
//
#include <hip/hip_runtime.h>

#define T_STEPS 64
#define BATCH   128
#define HID     1024
#define H3      3072
#define EMBD    1024
#define SLEN    128
#define BH      (BATCH * HID)

typedef __attribute__((ext_vector_type(8))) short short8;
typedef __attribute__((ext_vector_type(4))) float f32x4;

__device__ __forceinline__ unsigned short f2bf(float x) {
    unsigned int u = __float_as_uint(x);
    unsigned int r = (u + 0x7fffu + ((u >> 16) & 1u)) >> 16;
    return (unsigned short)r;
}
__device__ __forceinline__ float bf2f(unsigned short h) {
    return __uint_as_float(((unsigned int)h) << 16);
}
__device__ __forceinline__ unsigned int pk(unsigned short a, unsigned short b) {
    return (unsigned int)a | ((unsigned int)b << 16);
}
__device__ __forceinline__ void cvt8(const float4& x, const float4& y,
                                     uint4& H, uint4& L) {
    unsigned short h0 = f2bf(x.x), h1 = f2bf(x.y), h2 = f2bf(x.z), h3 = f2bf(x.w);
    unsigned short h4 = f2bf(y.x), h5 = f2bf(y.y), h6 = f2bf(y.z), h7 = f2bf(y.w);
    unsigned short l0 = f2bf(x.x - bf2f(h0)), l1 = f2bf(x.y - bf2f(h1));
    unsigned short l2 = f2bf(x.z - bf2f(h2)), l3 = f2bf(x.w - bf2f(h3));
    unsigned short l4 = f2bf(y.x - bf2f(h4)), l5 = f2bf(y.y - bf2f(h5));
    unsigned short l6 = f2bf(y.z - bf2f(h6)), l7 = f2bf(y.w - bf2f(h7));
    H = make_uint4(pk(h0,h1), pk(h2,h3), pk(h4,h5), pk(h6,h7));
    L = make_uint4(pk(l0,l1), pk(l2,l3), pk(l4,l5), pk(l6,l7));
}
__device__ __forceinline__ float sigf(float x) {
    return 1.f / (1.f + __expf(-x));
}

#define MF(A, B, ACC) ACC = __builtin_amdgcn_mfma_f32_16x16x32_bf16(A, B, ACC, 0, 0, 0)
#define TRI(AH, AL, WH, WL, ACC)  MF(AH, WL, ACC); MF(AL, WH, ACC); MF(AH, WH, ACC);

// ============== plane-conversion kernels (run once per call) ==============
template<bool LO>
__global__ __launch_bounds__(256) void conv_planes_k(
    const float* __restrict__ src, short* __restrict__ hi, short* __restrict__ lo)
{
    const long i8 = (long)blockIdx.x * 256 + threadIdx.x;
    float4 x = ((const float4*)src)[i8 * 2];
    float4 y = ((const float4*)src)[i8 * 2 + 1];
    uint4 H, L; cvt8(x, y, H, L);
    ((uint4*)hi)[i8] = H;
    if (LO) ((uint4*)lo)[i8] = L;
}

// 3 hi-only weight conversions fused (3 x 1536 blocks)
__global__ __launch_bounds__(256) void conv_w3_k(
    const float* __restrict__ s0, short* __restrict__ d0,
    const float* __restrict__ s1, short* __restrict__ d1,
    const float* __restrict__ s2, short* __restrict__ d2)
{
    const int id = blockIdx.x;
    const float* s; short* d; int sub;
    if (id < 1536)       { s = s0; d = d0; sub = id; }
    else if (id < 3072)  { s = s1; d = d1; sub = id - 1536; }
    else                 { s = s2; d = d2; sub = id - 3072; }
    const long i8 = (long)sub * 256 + threadIdx.x;
    float4 x = ((const float4*)s)[i8 * 2];
    float4 y = ((const float4*)s)[i8 * 2 + 1];
    uint4 H, L; cvt8(x, y, H, L);
    ((uint4*)d)[i8] = H;
    (void)L;
}

// L1 (512 blocks) + L2 (1024 blocks) hi/lo fused
__global__ __launch_bounds__(256) void conv_l12_k(
    const float* __restrict__ s0, short* __restrict__ h0p, short* __restrict__ l0p,
    const float* __restrict__ s1, short* __restrict__ h1p, short* __restrict__ l1p)
{
    const int id = blockIdx.x;
    const float* s; short* hh; short* ll; int sub;
    if (id < 512) { s = s0; hh = h0p; ll = l0p; sub = id; }
    else          { s = s1; hh = h1p; ll = l1p; sub = id - 512; }
    const long i8 = (long)sub * 256 + threadIdx.x;
    float4 x = ((const float4*)s)[i8 * 2];
    float4 y = ((const float4*)s)[i8 * 2 + 1];
    uint4 H, L; cvt8(x, y, H, L);
    ((uint4*)hh)[i8] = H;
    ((uint4*)ll)[i8] = L;
}

__global__ __launch_bounds__(256) void conv_gather_k(
    const float* __restrict__ emb, const int* __restrict__ input,
    short* __restrict__ hi, short* __restrict__ lo)
{
    const long i8 = (long)blockIdx.x * 256 + threadIdx.x;
    const int c8 = (int)(i8 & 127);
    const long row = i8 >> 7;
    const float* s = emb + (size_t)input[row] * 1024 + c8 * 8;
    float4 x = ((const float4*)s)[0];
    float4 y = ((const float4*)s)[1];
    uint4 H, L; cvt8(x, y, H, L);
    ((uint4*)hi)[i8] = H; ((uint4*)lo)[i8] = L;
}

// ============== tail GEMM: 128x64 block tile, 48 KB LDS (3 blocks/CU) ==============
// MODE 1: plane store   MODE 2: outf = tanh(acc).  Full TRI numerics.
template<int MODE, bool CONCAT>
__global__ __launch_bounds__(256) void gemm_b2(
    const short* __restrict__ A1h, const short* __restrict__ A1l,
    const short* __restrict__ A2h, const short* __restrict__ A2l,
    const short* __restrict__ Wh,  const short* __restrict__ Wl,
    int K, int nn,
    float* __restrict__ outf, short* __restrict__ outh, short* __restrict__ outl,
    int ldo)
{
    __shared__ short sm[24576];          // A: 2x8192, W: 2x4096 -> 48 KB
    short* Asm = sm;
    short* Wsm = sm + 16384;
    const int tid = threadIdx.x;
    const int wv = tid >> 6, l = tid & 63;
    const int mq = wv >> 1, nq = wv & 1;
    const int gl = l >> 4, r16 = l & 15;

    const int cpx = gridDim.x >> 3;
    const int id = blockIdx.x;
    const int swz = (id & 7) * cpx + (id >> 3);
    const int bm = swz / nn, bn = swz % nn;
    const long Rbase = (long)bm * 128;
    const int  Cbase = bn * 64;

    const int lda = CONCAT ? (K >> 1) : K;
    const int NC = K >> 5;
    const int NCh = NC >> 1;

    // A staging: 1024 slots (pl, row 0..127, kg 0..3), 4/thread
    const short *aP1[4], *aP2[4];
    int aLds[4];
    #pragma unroll
    for (int j = 0; j < 4; ++j) {
        const int s = tid + j * 256;
        const int pl = s >> 9, sp = s & 511;
        const int row = ((sp >> 6) << 4) | (sp & 15);
        const int kg = (sp >> 4) & 3;
        aLds[j] = s * 8;
        const short* a1 = pl ? A1l : A1h;
        aP1[j] = a1 + (Rbase + row) * (long)lda + kg * 8;
        if (CONCAT) {
            const short* a2 = pl ? A2l : A2h;
            aP2[j] = a2 + (Rbase + row) * (long)lda + kg * 8;
        } else aP2[j] = aP1[j];
    }
    // W staging: 512 slots (pl, row 0..63, kg 0..3), 2/thread
    const short* wP[2];
    int wLds[2];
    #pragma unroll
    for (int j = 0; j < 2; ++j) {
        const int s = tid + j * 256;
        const int pl = s >> 8, sp = s & 255;
        const int row = ((sp >> 6) << 4) | (sp & 15);
        const int kg = (sp >> 4) & 3;
        wLds[j] = s * 8;
        const short* wp = pl ? Wl : Wh;
        wP[j] = wp + ((long)Cbase + row) * (long)K + kg * 8;
    }

    f32x4 acc[4][2];
    #pragma unroll
    for (int i = 0; i < 4; ++i) {
        acc[i][0] = (f32x4)0.f;
        acc[i][1] = (f32x4)0.f;
    }

    short8 rA[4], rW[2];
    auto LOADC = [&](int c) {
        const bool p1 = !CONCAT || (c < NCh);
        const long ko = p1 ? (long)c * 32 : (long)c * 32 - (K >> 1);
        #pragma unroll
        for (int j = 0; j < 4; ++j)
            rA[j] = *(const short8*)((p1 ? aP1[j] : aP2[j]) + ko);
        #pragma unroll
        for (int j = 0; j < 2; ++j)
            rW[j] = *(const short8*)(wP[j] + (long)c * 32);
    };
    auto STORE = [&](int c) {
        const int ba = (c & 1) << 13;
        const int bw = (c & 1) << 12;
        #pragma unroll
        for (int j = 0; j < 4; ++j)
            *(short8*)(Asm + ba + aLds[j]) = rA[j];
        #pragma unroll
        for (int j = 0; j < 2; ++j)
            *(short8*)(Wsm + bw + wLds[j]) = rW[j];
    };

    LOADC(0); STORE(0); LOADC(1);
    __syncthreads();

    for (int c = 0; c < NC; ++c) {
        const int ba = (c & 1) << 13;
        const int bw = (c & 1) << 12;
        short8 ah[4], al[4], wh[2], wl[2];
        #pragma unroll
        for (int f = 0; f < 4; ++f) {
            const short* ab = Asm + ba + ((mq * 4 + f) * 64 + l) * 8;
            ah[f] = *(const short8*)ab;
            al[f] = *(const short8*)(ab + 4096);
        }
        #pragma unroll
        for (int f = 0; f < 2; ++f) {
            const short* wb = Wsm + bw + ((nq * 2 + f) * 64 + l) * 8;
            wh[f] = *(const short8*)wb;
            wl[f] = *(const short8*)(wb + 2048);
        }
        if (c + 1 < NC) STORE(c + 1);
        if (c + 2 < NC) LOADC(c + 2);
        #pragma unroll
        for (int mf = 0; mf < 4; ++mf)
            #pragma unroll
            for (int nf = 0; nf < 2; ++nf) {
                TRI(ah[mf], al[mf], wh[nf], wl[nf], acc[mf][nf]);
            }
        __syncthreads();
    }

    #pragma unroll
    for (int mf = 0; mf < 4; ++mf) {
        #pragma unroll
        for (int reg = 0; reg < 4; ++reg) {
            const long R = Rbase + mq * 64 + mf * 16 + gl * 4 + reg;
            #pragma unroll
            for (int nf = 0; nf < 2; ++nf) {
                const int col = Cbase + nq * 32 + nf * 16 + r16;
                const float v = acc[mf][nf][reg];
                if constexpr (MODE == 1) {
                    const unsigned short hi = f2bf(v), lo = f2bf(v - bf2f(hi));
                    outh[R * (long)ldo + col] = (short)hi;
                    outl[R * (long)ldo + col] = (short)lo;
                } else {
                    outf[R * (long)ldo + col] = tanhf(v);
                }
            }
        }
    }
}

// ============== recurrence GEMM core — K=1024, R11 staging/prefetch ==============
// MODE 0: gi-GEMM TRI (W hi+lo) -> f32 stride-H3 out (+bias).
// MODE 1: gi-GEMM DUO (W hi)    -> f32 stride-H3 out (+bias).
// MODE 3: gate DUO; gif = i-side f32 (stride H3); writes h f32 + planes
//         (+ optional second f32 copy to outf2 for the final step).
template<int MODE>
__device__ __forceinline__ void gru_core(
    int bm, int bj,
    const short* __restrict__ Ah, const short* __restrict__ Al,
    const short* __restrict__ Wh,  const short* __restrict__ Wl,
    const float* __restrict__ bias,
    const float* __restrict__ gif,
    const float* __restrict__ hprev,
    float* __restrict__ outf,
    short* __restrict__ outh, short* __restrict__ outl,
    float* __restrict__ outf2)
{
    extern __shared__ short sm[];
    constexpr int P = 3;
    constexpr int NC = 16;                 // K = 1024
    constexpr bool WL = (MODE == 0);       // need W lo plane (TRI)
    const int ABUF = 8192, WBUF = P * 2048;
    short* Asm = sm;
    short* Wsm = sm + 2 * ABUF;
    const int tid = threadIdx.x;
    const int wv = tid >> 6, l = tid & 63;
    const int gl = l >> 4, r16 = l & 15;

    const short *ahP[2], *alP[2];
    int aLds[2];
    #pragma unroll
    for (int i = 0; i < 2; ++i) {
        const int s = tid + i * 256;
        const int row = ((s >> 6) & 3) * 16 + (s & 15);
        const int kg  = ((s >> 8) << 2) | ((s >> 4) & 3);
        const long r = (long)bm * 64 + row;
        ahP[i] = Ah + r * HID + kg * 8;
        alP[i] = Al + r * HID + kg * 8;
        aLds[i] = s * 8;
    }
    const bool doW = tid < P * 64;
    const short *whP[2], *wlP[2];
    int wLds[2] = {0, 0};
    if (doW) {
        #pragma unroll
        for (int i = 0; i < 2; ++i) {
            const int s = tid + i * P * 64;
            const int kcw = s / (P * 64);
            const int rem = s - kcw * (P * 64);
            const int p = rem >> 6, ll = rem & 63;
            const int jr = ll & 15, g = ll >> 4;
            const int kg = kcw * 4 + g;
            const long grow = (long)(p << 10) + bj * 16 + jr;
            whP[i] = Wh + grow * (long)HID + kg * 8;
            wlP[i] = WL ? Wl + grow * (long)HID + kg * 8 : whP[i];
            wLds[i] = s * 8;
        }
    }

    f32x4 acc[P];
    #pragma unroll
    for (int i = 0; i < P; ++i) acc[i] = (f32x4)0.f;

    short8 rAh[2], rAl[2], rWh[2], rWl[2];
    auto LOADC = [&](int c) {
        const long ko = (long)c * 64;
        #pragma unroll
        for (int i = 0; i < 2; ++i) {
            rAh[i] = *(const short8*)(ahP[i] + ko);
            rAl[i] = *(const short8*)(alP[i] + ko);
        }
        if (doW) {
            #pragma unroll
            for (int i = 0; i < 2; ++i) {
                rWh[i] = *(const short8*)(whP[i] + ko);
                if (WL) rWl[i] = *(const short8*)(wlP[i] + ko);
            }
        }
    };
    auto STORE = [&](int c) {
        const int b = c & 1;
        #pragma unroll
        for (int i = 0; i < 2; ++i) {
            *(short8*)(Asm + b * ABUF + aLds[i]) = rAh[i];
            *(short8*)(Asm + b * ABUF + 4096 + aLds[i]) = rAl[i];
        }
        if (doW) {
            #pragma unroll
            for (int i = 0; i < 2; ++i) {
                *(short8*)(Wsm + b * WBUF + wLds[i]) = rWh[i];
                if (WL) *(short8*)(Wsm + b * WBUF + P * 1024 + wLds[i]) = rWl[i];
            }
        }
    };

    LOADC(0); STORE(0); LOADC(1);
    __syncthreads();

    for (int c = 0; c < NC; ++c) {
        const int b = c & 1;
        short8 fah[2], fal[2], fwh[2][P], fwl[2][P];
        #pragma unroll
        for (int kc = 0; kc < 2; ++kc) {
            const short* ab = Asm + b * ABUF + (kc * 256 + wv * 64 + l) * 8;
            fah[kc] = *(const short8*)ab;
            fal[kc] = *(const short8*)(ab + 4096);
            #pragma unroll
            for (int p = 0; p < P; ++p) {
                const short* wb = Wsm + b * WBUF + (kc * (P * 64) + p * 64 + l) * 8;
                fwh[kc][p] = *(const short8*)wb;
                if (WL) fwl[kc][p] = *(const short8*)(wb + P * 1024);
            }
        }
        if (c + 1 < NC) STORE(c + 1);
        if (c + 2 < NC) LOADC(c + 2);
        #pragma unroll
        for (int kc = 0; kc < 2; ++kc) {
            #pragma unroll
            for (int p = 0; p < P; ++p) {
                if constexpr (MODE == 0) {
                    TRI(fah[kc], fal[kc], fwh[kc][p], fwl[kc][p], acc[p]);
                } else {
                    MF(fal[kc], fwh[kc][p], acc[p]);
                    MF(fah[kc], fwh[kc][p], acc[p]);
                }
            }
        }
        __syncthreads();
    }

    const int jc = bj * 16 + r16;
    #pragma unroll
    for (int reg = 0; reg < 4; ++reg) {
        const long R = (long)bm * 64 + wv * 16 + gl * 4 + reg;
        if constexpr (MODE != 3) {
            #pragma unroll
            for (int p = 0; p < P; ++p)
                outf[R * H3 + p * HID + jc] = acc[p][reg] + bias[p * HID + jc];
        } else {
            const float* orow = gif + R * H3;
            const float rr = sigf(orow[jc] + acc[0][reg] + bias[jc]);
            const float zz = sigf(orow[HID + jc] + acc[1][reg] + bias[HID + jc]);
            const float nn = tanhf(orow[2 * HID + jc] + rr * (acc[2][reg] + bias[2 * HID + jc]));
            const float h = (1.f - zz) * nn + zz * hprev[R * HID + jc];
            outf[R * HID + jc] = h;
            if (outf2) outf2[R * HID + jc] = h;
            const unsigned short hb = f2bf(h), lb = f2bf(h - bf2f(hb));
            outh[R * HID + jc] = (short)hb;
            outl[R * HID + jc] = (short)lb;
        }
    }
}

// ============== 4-role pipelined step kernel (512 blocks, XCD-pinned) ==============
struct StepP {
    const short* hih; const short* hil;
    const float* h_in;
    const short* eqh; const short* eql;
    float* gi0; float* gi1;
    const short* whh0h; const short* wih0h;
    const short* wih1h; const short* wih1l; const short* whh1h;
    const float* b_ih0; const float* b_hh0; const float* b_ih1; const float* b_hh1;
    float* h0f; float* h1f;
    short* h0ah; short* h0al; short* h1ah; short* h1al;
    float* hf0dst; float* hf1dst;     // d_out final-state tail
};

__global__ __launch_bounds__(256) void step_k(int ph, StepP P)
{
    const int id = blockIdx.x;
    const int xcd = id & 7, sub = (id >> 3) & 7, top = id >> 6;
    const int role = top >> 1, bm = top & 1;
    const int bj = xcd * 8 + sub;

    if (role == 0) {
        const int t = ph;
        if (t >= T_STEPS) return;
        const short* a1h = t ? P.h0ah + (size_t)(t - 1) * BH : P.hih;
        const short* a1l = t ? P.h0al + (size_t)(t - 1) * BH : P.hil;
        gru_core<3>(bm, bj, a1h, a1l, P.whh0h, nullptr, P.b_hh0,
                    P.gi0 + (size_t)t * BATCH * H3,
                    t ? P.h0f + (size_t)((t - 1) & 1) * BH : P.h_in,
                    P.h0f + (size_t)(t & 1) * BH,
                    P.h0ah + (size_t)t * BH, P.h0al + (size_t)t * BH,
                    (t == T_STEPS - 1) ? P.hf0dst : nullptr);
    } else if (role == 1) {
        const int s = ph - 1;
        if (s < 0 || s >= T_STEPS) return;
        gru_core<0>(bm, bj,
                    P.h0ah + (size_t)s * BH, P.h0al + (size_t)s * BH,
                    P.wih1h, P.wih1l, P.b_ih1,
                    nullptr, nullptr,
                    P.gi1 + (size_t)(s & 1) * BATCH * H3,
                    nullptr, nullptr, nullptr);
    } else if (role == 2) {
        const int s = ph - 2;
        if (s < 0 || s >= T_STEPS) return;
        const short* a1h = s ? P.h1ah + (size_t)(s - 1) * BH : P.hih + BH;
        const short* a1l = s ? P.h1al + (size_t)(s - 1) * BH : P.hil + BH;
        gru_core<3>(bm, bj, a1h, a1l, P.whh1h, nullptr, P.b_hh1,
                    P.gi1 + (size_t)(s & 1) * BATCH * H3,
                    s ? P.h1f + (size_t)((s - 1) & 1) * BH : P.h_in + BH,
                    P.h1f + (size_t)(s & 1) * BH,
                    P.h1ah + (size_t)s * BH, P.h1al + (size_t)s * BH,
                    (s == T_STEPS - 1) ? P.hf1dst : nullptr);
    } else {
        const int u = ph + 2;
        if (u >= T_STEPS) return;
        gru_core<1>(bm, bj,
                    P.eqh + (size_t)u * BH, P.eql + (size_t)u * BH,
                    P.wih0h, nullptr, P.b_ih0,
                    nullptr, nullptr,
                    P.gi0 + (size_t)u * BATCH * H3,
                    nullptr, nullptr, nullptr);
    }
}

// prologue: gi0 for steps 0..1 (256 blocks: t=id>>7, bm=(id>>6)&1, bj=id&63)
__global__ __launch_bounds__(256) void step_pre_k(StepP P)
{
    const int id = blockIdx.x;
    const int t = id >> 7, bm = (id >> 6) & 1, bj = id & 63;
    gru_core<1>(bm, bj,
                P.eqh + (size_t)t * BH, P.eql + (size_t)t * BH,
                P.wih0h, nullptr, P.b_ih0,
                nullptr, nullptr,
                P.gi0 + (size_t)t * BATCH * H3,
                nullptr, nullptr, nullptr);
}

// ============== batched attention scores + softmax (per b) ==============
__global__ __launch_bounds__(256) void scores_k(
    const short* __restrict__ Qh, const short* __restrict__ Ql,
    const short* __restrict__ Hh, const short* __restrict__ Hl,
    float* __restrict__ Pall)
{
    extern __shared__ short sm[];
    short* Asm = sm;
    short* Wsm = sm + 8192;
    const int b = blockIdx.x, tid = threadIdx.x;
    const int wv = tid >> 6, l = tid & 63;
    const int gl = l >> 4, cc = l & 15;

    const int arow = ((tid >> 6) & 3) * 16 + (tid & 15);
    const int ag   = (tid >> 4) & 3;
    const short* qhp = Qh + ((long)arow * BATCH + b) * HID + ag * 8;
    const short* qlp = Ql + ((long)arow * BATCH + b) * HID + ag * 8;
    const int aLds = tid * 8;

    const short *whp[2], *wlp[2]; int wLds[2];
    #pragma unroll
    for (int i = 0; i < 2; ++i) {
        const int s = tid + i * 256;
        const int srow = ((s >> 6) & 7) * 16 + (s & 15);
        const int sg   = (s >> 4) & 3;
        whp[i] = Hh + ((long)srow * BATCH + b) * HID + sg * 8;
        wlp[i] = Hl + ((long)srow * BATCH + b) * HID + sg * 8;
        wLds[i] = s * 8;
    }

    f32x4 acc[8];
    #pragma unroll
    for (int i = 0; i < 8; ++i) acc[i] = (f32x4)0.f;

    short8 rAh, rAl, rWh[2], rWl[2];
    auto LOADC = [&](int c) {
        rAh = *(const short8*)(qhp + c * 32);
        rAl = *(const short8*)(qlp + c * 32);
        #pragma unroll
        for (int i = 0; i < 2; ++i) {
            rWh[i] = *(const short8*)(whp[i] + c * 32);
            rWl[i] = *(const short8*)(wlp[i] + c * 32);
        }
    };
    auto STORE = [&](int c) {
        const int bb = c & 1;
        *(short8*)(Asm + bb * 4096 + aLds) = rAh;
        *(short8*)(Asm + bb * 4096 + 2048 + aLds) = rAl;
        #pragma unroll
        for (int i = 0; i < 2; ++i) {
            *(short8*)(Wsm + bb * 8192 + wLds[i]) = rWh[i];
            *(short8*)(Wsm + bb * 8192 + 4096 + wLds[i]) = rWl[i];
        }
    };

    LOADC(0); STORE(0); LOADC(1);
    __syncthreads();
    for (int c = 0; c < 32; ++c) {
        const int bb = c & 1;
        const short* abp = Asm + bb * 4096 + (wv * 64 + l) * 8;
        short8 ah = *(const short8*)abp;
        short8 al = *(const short8*)(abp + 2048);
        if (c + 1 < 32) STORE(c + 1);
        if (c + 2 < 32) LOADC(c + 2);
        #pragma unroll
        for (int jt = 0; jt < 8; ++jt) {
            const short* wbp = Wsm + bb * 8192 + (jt * 64 + l) * 8;
            short8 wh = *(const short8*)wbp;
            short8 wl = *(const short8*)(wbp + 4096);
            TRI(ah, al, wh, wl, acc[jt]);
        }
        __syncthreads();
    }

    #pragma unroll
    for (int reg = 0; reg < 4; ++reg) {
        float m = acc[0][reg];
        #pragma unroll
        for (int jt = 1; jt < 8; ++jt) m = fmaxf(m, acc[jt][reg]);
        #pragma unroll
        for (int off = 1; off < 16; off <<= 1) m = fmaxf(m, __shfl_xor(m, off));
        float e[8], ssum = 0.f;
        #pragma unroll
        for (int jt = 0; jt < 8; ++jt) { e[jt] = __expf(acc[jt][reg] - m); ssum += e[jt]; }
        #pragma unroll
        for (int off = 1; off < 16; off <<= 1) ssum += __shfl_xor(ssum, off);
        const float inv = 1.f / ssum;
        const int t = wv * 16 + gl * 4 + reg;
        #pragma unroll
        for (int jt = 0; jt < 8; ++jt)
            Pall[((long)t * BATCH + b) * SLEN + jt * 16 + cc] = e[jt] * inv;
    }
}

__global__ __launch_bounds__(256) void ctx_k(
    const float* __restrict__ Pall, const float* __restrict__ H,
    short* __restrict__ Ch, short* __restrict__ Cl)
{
    __shared__ float Ps[T_STEPS * SLEN];
    const int b = blockIdx.x, ht = blockIdx.y, tid = threadIdx.x;
    for (int i = 0; i < 32; ++i) {
        const int idx = i * 256 + tid;
        const int t = idx >> 7, s = idx & 127;
        Ps[idx] = Pall[((long)t * BATCH + b) * SLEN + s];
    }
    __syncthreads();
    const int col = ht * 256 + tid;
    for (int tg = 0; tg < 4; ++tg) {
        float a[16];
        #pragma unroll
        for (int j = 0; j < 16; ++j) a[j] = 0.f;
        for (int s = 0; s < SLEN; ++s) {
            const float hv = H[((long)s * BATCH + b) * HID + col];
            #pragma unroll
            for (int j = 0; j < 16; ++j)
                a[j] = fmaf(Ps[(tg * 16 + j) * SLEN + s], hv, a[j]);
        }
        #pragma unroll
        for (int j = 0; j < 16; ++j) {
            const long row = (long)(tg * 16 + j) * BATCH + b;
            const unsigned short hi = f2bf(a[j]);
            const unsigned short lo = f2bf(a[j] - bf2f(hi));
            Ch[row * HID + col] = (short)hi;
            Cl[row * HID + col] = (short)lo;
        }
    }
}

// =========================== launch ===========================
extern "C" void kernel_launch(void* const* d_in, const int* in_sizes, int n_in,
                              void* d_out, int out_size, void* d_ws, size_t ws_size,
                              hipStream_t stream)
{
    const int*   input = (const int*)  d_in[0];
    const float* h_in  = (const float*)d_in[1];
    const float* Hbuf  = (const float*)d_in[2];
    const float* emb   = (const float*)d_in[3];
    const float* w_ih  = (const float*)d_in[4];
    const float* w_hh  = (const float*)d_in[5];
    const float* b_ih  = (const float*)d_in[6];
    const float* b_hh  = (const float*)d_in[7];
    const float* L1    = (const float*)d_in[8];
    const float* L2    = (const float*)d_in[9];

    float* out = (float*)d_out;

    char* basep = (char*)d_ws;
    size_t off = 0;
    auto alloc = [&](size_t bytes) -> char* {
        off = (off + 255) & ~(size_t)255;
        char* p = basep + off; off += bytes; return p;
    };
    short* wih0h = (short*)alloc(3072L*1024*2);
    short* whh0h = (short*)alloc(3072L*1024*2);
    short* wih1h = (short*)alloc(3072L*1024*2); short* wih1l = (short*)alloc(3072L*1024*2);
    short* whh1h = (short*)alloc(3072L*1024*2);
    short* l1h   = (short*)alloc(1024L*1024*2); short* l1l   = (short*)alloc(1024L*1024*2);
    short* l2h   = (short*)alloc(1024L*2048*2); short* l2l   = (short*)alloc(1024L*2048*2);
    short* Hh    = (short*)alloc(16777216L*2);  short* Hl    = (short*)alloc(16777216L*2);
    short* hih   = (short*)alloc(262144L*2);    short* hil   = (short*)alloc(262144L*2);
    short* h0ah  = (short*)alloc(8388608L*2);   short* h0al  = (short*)alloc(8388608L*2);
    short* h1ah  = (short*)alloc(8388608L*2);   short* h1al  = (short*)alloc(8388608L*2);
    short* eqh   = (short*)alloc(8388608L*2);   short* eql   = (short*)alloc(8388608L*2);
    float* gi0   = (float*)alloc(25165824L*4);
    float* gi1   = (float*)alloc(2L*BATCH*H3*4);
    float* h0f   = (float*)alloc(524288L*4);
    float* h1f   = (float*)alloc(524288L*4);
    float* Pall  = (float*)alloc(1048576L*4);
    short* ctxh  = (short*)gi0;                 // gi0 dead after step loop
    short* ctxl  = ctxh + 8388608L;

    const dim3 blk(256);
    const size_t SM3 = (2 * 8192 + 2 * 3 * 2048) * sizeof(short);  // 57344

    // ---- phase 0: plane conversions (fused) ----
    conv_w3_k<<<4608, blk, 0, stream>>>(w_ih, wih0h,
                                        w_hh, whh0h,
                                        w_hh + 3145728L, whh1h);
    conv_planes_k<true ><<<1536, blk, 0, stream>>>(w_ih + 3145728L, wih1h, wih1l);
    conv_l12_k<<<1536, blk, 0, stream>>>(L1, l1h, l1l, L2, l2h, l2l);
    conv_planes_k<true ><<<8192, blk, 0, stream>>>(Hbuf, Hh, Hl);
    conv_planes_k<true ><<<128,  blk, 0, stream>>>(h_in, hih, hil);
    conv_gather_k<<<4096, blk, 0, stream>>>(emb, input, eqh, eql);

    // ---- 4-role pipelined recurrence ----
    StepP sp;
    sp.hih = hih; sp.hil = hil; sp.h_in = h_in;
    sp.eqh = eqh; sp.eql = eql;
    sp.gi0 = gi0; sp.gi1 = gi1;
    sp.whh0h = whh0h; sp.wih0h = wih0h;
    sp.wih1h = wih1h; sp.wih1l = wih1l; sp.whh1h = whh1h;
    sp.b_ih0 = b_ih; sp.b_hh0 = b_hh;
    sp.b_ih1 = b_ih + H3; sp.b_hh1 = b_hh + H3;
    sp.h0f = h0f; sp.h1f = h1f;
    sp.h0ah = h0ah; sp.h0al = h0al; sp.h1ah = h1ah; sp.h1al = h1al;
    sp.hf0dst = out + (long)T_STEPS * BH;
    sp.hf1dst = out + (long)T_STEPS * BH + BH;

    step_pre_k<<<dim3(256), blk, SM3, stream>>>(sp);    // gi0[0..1]
    for (int ph = 0; ph <= T_STEPS + 1; ++ph)
        step_k<<<dim3(512), blk, SM3, stream>>>(ph, sp);

    // ---- batched attention + output (128x64-tile tail GEMMs) ----
    gemm_b2<1, false><<<dim3(1024), blk, 0, stream>>>(
        h1ah, h1al, nullptr, nullptr, l1h, l1l, 1024, 16,
        nullptr, eqh, eql, HID);
    scores_k<<<dim3(BATCH), blk, 49152, stream>>>(eqh, eql, Hh, Hl, Pall);
    ctx_k<<<dim3(BATCH, 4), blk, 0, stream>>>(Pall, Hbuf, ctxh, ctxl);
    gemm_b2<2, true><<<dim3(1024), blk, 0, stream>>>(
        ctxh, ctxl, h1ah, h1al, l2h, l2l, 2048, 16,
        out, nullptr, nullptr, HID);
}

// Round 19
// 1986.718 us; speedup vs baseline: 1.0378x; 1.0378x over previous
//
#include <hip/hip_runtime.h>

#define T_STEPS 64
#define BATCH   128
#define HID     1024
#define H3      3072
#define EMBD    1024
#define SLEN    128
#define BH      (BATCH * HID)

typedef __attribute__((ext_vector_type(8))) short short8;
typedef __attribute__((ext_vector_type(4))) float f32x4;

__device__ __forceinline__ unsigned short f2bf(float x) {
    unsigned int u = __float_as_uint(x);
    unsigned int r = (u + 0x7fffu + ((u >> 16) & 1u)) >> 16;
    return (unsigned short)r;
}
__device__ __forceinline__ float bf2f(unsigned short h) {
    return __uint_as_float(((unsigned int)h) << 16);
}
__device__ __forceinline__ unsigned int pk(unsigned short a, unsigned short b) {
    return (unsigned int)a | ((unsigned int)b << 16);
}
__device__ __forceinline__ void cvt8(const float4& x, const float4& y,
                                     uint4& H, uint4& L) {
    unsigned short h0 = f2bf(x.x), h1 = f2bf(x.y), h2 = f2bf(x.z), h3 = f2bf(x.w);
    unsigned short h4 = f2bf(y.x), h5 = f2bf(y.y), h6 = f2bf(y.z), h7 = f2bf(y.w);
    unsigned short l0 = f2bf(x.x - bf2f(h0)), l1 = f2bf(x.y - bf2f(h1));
    unsigned short l2 = f2bf(x.z - bf2f(h2)), l3 = f2bf(x.w - bf2f(h3));
    unsigned short l4 = f2bf(y.x - bf2f(h4)), l5 = f2bf(y.y - bf2f(h5));
    unsigned short l6 = f2bf(y.z - bf2f(h6)), l7 = f2bf(y.w - bf2f(h7));
    H = make_uint4(pk(h0,h1), pk(h2,h3), pk(h4,h5), pk(h6,h7));
    L = make_uint4(pk(l0,l1), pk(l2,l3), pk(l4,l5), pk(l6,l7));
}
__device__ __forceinline__ float sigf(float x) {
    return 1.f / (1.f + __expf(-x));
}

#define MF(A, B, ACC) ACC = __builtin_amdgcn_mfma_f32_16x16x32_bf16(A, B, ACC, 0, 0, 0)
#define TRI(AH, AL, WH, WL, ACC)  MF(AH, WL, ACC); MF(AL, WH, ACC); MF(AH, WH, ACC);

// ============== plane-conversion kernels (run once per call) ==============
template<bool LO>
__global__ __launch_bounds__(256) void conv_planes_k(
    const float* __restrict__ src, short* __restrict__ hi, short* __restrict__ lo)
{
    const long i8 = (long)blockIdx.x * 256 + threadIdx.x;
    float4 x = ((const float4*)src)[i8 * 2];
    float4 y = ((const float4*)src)[i8 * 2 + 1];
    uint4 H, L; cvt8(x, y, H, L);
    ((uint4*)hi)[i8] = H;
    if (LO) ((uint4*)lo)[i8] = L;
}

// 3 hi-only weight conversions fused (3 x 1536 blocks)
__global__ __launch_bounds__(256) void conv_w3_k(
    const float* __restrict__ s0, short* __restrict__ d0,
    const float* __restrict__ s1, short* __restrict__ d1,
    const float* __restrict__ s2, short* __restrict__ d2)
{
    const int id = blockIdx.x;
    const float* s; short* d; int sub;
    if (id < 1536)       { s = s0; d = d0; sub = id; }
    else if (id < 3072)  { s = s1; d = d1; sub = id - 1536; }
    else                 { s = s2; d = d2; sub = id - 3072; }
    const long i8 = (long)sub * 256 + threadIdx.x;
    float4 x = ((const float4*)s)[i8 * 2];
    float4 y = ((const float4*)s)[i8 * 2 + 1];
    uint4 H, L; cvt8(x, y, H, L);
    ((uint4*)d)[i8] = H;
    (void)L;
}

// L1 (512 blocks) + L2 (1024 blocks) hi/lo fused
__global__ __launch_bounds__(256) void conv_l12_k(
    const float* __restrict__ s0, short* __restrict__ h0p, short* __restrict__ l0p,
    const float* __restrict__ s1, short* __restrict__ h1p, short* __restrict__ l1p)
{
    const int id = blockIdx.x;
    const float* s; short* hh; short* ll; int sub;
    if (id < 512) { s = s0; hh = h0p; ll = l0p; sub = id; }
    else          { s = s1; hh = h1p; ll = l1p; sub = id - 512; }
    const long i8 = (long)sub * 256 + threadIdx.x;
    float4 x = ((const float4*)s)[i8 * 2];
    float4 y = ((const float4*)s)[i8 * 2 + 1];
    uint4 H, L; cvt8(x, y, H, L);
    ((uint4*)hh)[i8] = H;
    ((uint4*)ll)[i8] = L;
}

__global__ __launch_bounds__(256) void conv_gather_k(
    const float* __restrict__ emb, const int* __restrict__ input,
    short* __restrict__ hi, short* __restrict__ lo)
{
    const long i8 = (long)blockIdx.x * 256 + threadIdx.x;
    const int c8 = (int)(i8 & 127);
    const long row = i8 >> 7;
    const float* s = emb + (size_t)input[row] * 1024 + c8 * 8;
    float4 x = ((const float4*)s)[0];
    float4 y = ((const float4*)s)[1];
    uint4 H, L; cvt8(x, y, H, L);
    ((uint4*)hi)[i8] = H; ((uint4*)lo)[i8] = L;
}

// ============== big batched GEMM: 128x128 block tile ==============
// MODE 1: plane store (+bias if given)   MODE 2: outf = tanh(acc)
template<int MODE, bool CONCAT, bool WLO>
__global__ __launch_bounds__(256, 2) void gemm_big(
    const short* __restrict__ A1h, const short* __restrict__ A1l,
    const short* __restrict__ A2h, const short* __restrict__ A2l,
    const short* __restrict__ Wh,  const short* __restrict__ Wl,
    int K, int nn,
    const float* __restrict__ bias,
    float* __restrict__ outf, short* __restrict__ outh, short* __restrict__ outl,
    int ldo)
{
    extern __shared__ short sm[];
    short* Asm = sm;
    short* Wsm = sm + 16384;
    const int tid = threadIdx.x;
    const int wv = tid >> 6, l = tid & 63;
    const int mq = wv >> 1, nq = wv & 1;
    const int gl = l >> 4, r16 = l & 15;

    const int cpx = gridDim.x >> 3;
    const int id = blockIdx.x;
    const int swz = (id & 7) * cpx + (id >> 3);
    const int bm = swz / nn, bn = swz % nn;
    const long Rbase = (long)bm * 128;
    const int  Cbase = bn * 128;

    const int lda = CONCAT ? (K >> 1) : K;
    const int NC = K >> 5;
    const int NCh = NC >> 1;

    const short *aP1[4], *aP2[4], *wP[4];
    int slda[4];
    #pragma unroll
    for (int j = 0; j < 4; ++j) {
        const int s = tid + j * 256;
        const int pl = s >> 9, sp = s & 511;
        const int row = ((sp >> 6) << 4) | (sp & 15);
        const int kg = (sp >> 4) & 3;
        slda[j] = s * 8;
        const short* a1 = pl ? A1l : A1h;
        aP1[j] = a1 + (Rbase + row) * (long)lda + kg * 8;
        if (CONCAT) {
            const short* a2 = pl ? A2l : A2h;
            aP2[j] = a2 + (Rbase + row) * (long)lda + kg * 8;
        } else aP2[j] = aP1[j];
        const short* wp = pl ? Wl : Wh;
        wP[j] = wp + ((long)Cbase + row) * (long)K + kg * 8;
    }

    f32x4 acc[4][4];
    #pragma unroll
    for (int i = 0; i < 4; ++i)
        #pragma unroll
        for (int j = 0; j < 4; ++j) acc[i][j] = (f32x4)0.f;

    short8 rA[4], rW[4];
    auto LOADC = [&](int c) {
        const bool p1 = !CONCAT || (c < NCh);
        const long ko = p1 ? (long)c * 32 : (long)c * 32 - (K >> 1);
        #pragma unroll
        for (int j = 0; j < 4; ++j) {
            rA[j] = *(const short8*)((p1 ? aP1[j] : aP2[j]) + ko);
            if (!WLO || j < 2)
                rW[j] = *(const short8*)(wP[j] + (long)c * 32);
        }
    };
    auto STORE = [&](int c) {
        const int b = (c & 1) << 13;
        #pragma unroll
        for (int j = 0; j < 4; ++j) {
            *(short8*)(Asm + b + slda[j]) = rA[j];
            if (!WLO || j < 2)
                *(short8*)(Wsm + b + slda[j]) = rW[j];
        }
    };

    LOADC(0); STORE(0); LOADC(1);
    __syncthreads();

    for (int c = 0; c < NC; ++c) {
        const int b = (c & 1) << 13;
        short8 ah[4], al[4], wh[4], wl[4];
        #pragma unroll
        for (int f = 0; f < 4; ++f) {
            const short* ab = Asm + b + ((mq * 4 + f) * 64 + l) * 8;
            ah[f] = *(const short8*)ab;
            al[f] = *(const short8*)(ab + 4096);
            const short* wb = Wsm + b + ((nq * 4 + f) * 64 + l) * 8;
            wh[f] = *(const short8*)wb;
            if (!WLO) wl[f] = *(const short8*)(wb + 4096);
        }
        if (c + 1 < NC) STORE(c + 1);
        if (c + 2 < NC) LOADC(c + 2);
        #pragma unroll
        for (int mf = 0; mf < 4; ++mf)
            #pragma unroll
            for (int nf = 0; nf < 4; ++nf) {
                if constexpr (WLO) {
                    MF(al[mf], wh[nf], acc[mf][nf]);
                    MF(ah[mf], wh[nf], acc[mf][nf]);
                } else {
                    TRI(ah[mf], al[mf], wh[nf], wl[nf], acc[mf][nf]);
                }
            }
        __syncthreads();
    }

    #pragma unroll
    for (int mf = 0; mf < 4; ++mf) {
        #pragma unroll
        for (int reg = 0; reg < 4; ++reg) {
            const long R = Rbase + mq * 64 + mf * 16 + gl * 4 + reg;
            #pragma unroll
            for (int nf = 0; nf < 4; ++nf) {
                const int col = Cbase + nq * 64 + nf * 16 + r16;
                float v = acc[mf][nf][reg];
                if constexpr (MODE == 1) {
                    if (bias) v += bias[col];
                    const unsigned short hi = f2bf(v), lo = f2bf(v - bf2f(hi));
                    outh[R * (long)ldo + col] = (short)hi;
                    outl[R * (long)ldo + col] = (short)lo;
                } else {
                    outf[R * (long)ldo + col] = tanhf(v);
                }
            }
        }
    }
}

// ============== recurrence GEMM core — K=1024, R11 staging/prefetch ==============
// MODE 0: gi-GEMM TRI (W hi+lo) -> f32 stride-H3 out (+bias).
// MODE 1: gi-GEMM DUO (W hi)    -> f32 stride-H3 out (+bias).
// MODE 3: gate DUO; gif = i-side f32 (stride H3); writes h f32 + planes
//         (+ optional second f32 copy to outf2 for the final step).
template<int MODE>
__device__ __forceinline__ void gru_core(
    int bm, int bj,
    const short* __restrict__ Ah, const short* __restrict__ Al,
    const short* __restrict__ Wh,  const short* __restrict__ Wl,
    const float* __restrict__ bias,
    const float* __restrict__ gif,
    const float* __restrict__ hprev,
    float* __restrict__ outf,
    short* __restrict__ outh, short* __restrict__ outl,
    float* __restrict__ outf2)
{
    extern __shared__ short sm[];
    constexpr int P = 3;
    constexpr int NC = 16;                 // K = 1024
    constexpr bool WL = (MODE == 0);       // need W lo plane (TRI)
    const int ABUF = 8192, WBUF = P * 2048;
    short* Asm = sm;
    short* Wsm = sm + 2 * ABUF;
    const int tid = threadIdx.x;
    const int wv = tid >> 6, l = tid & 63;
    const int gl = l >> 4, r16 = l & 15;

    const short *ahP[2], *alP[2];
    int aLds[2];
    #pragma unroll
    for (int i = 0; i < 2; ++i) {
        const int s = tid + i * 256;
        const int row = ((s >> 6) & 3) * 16 + (s & 15);
        const int kg  = ((s >> 8) << 2) | ((s >> 4) & 3);
        const long r = (long)bm * 64 + row;
        ahP[i] = Ah + r * HID + kg * 8;
        alP[i] = Al + r * HID + kg * 8;
        aLds[i] = s * 8;
    }
    const bool doW = tid < P * 64;
    const short *whP[2], *wlP[2];
    int wLds[2] = {0, 0};
    if (doW) {
        #pragma unroll
        for (int i = 0; i < 2; ++i) {
            const int s = tid + i * P * 64;
            const int kcw = s / (P * 64);
            const int rem = s - kcw * (P * 64);
            const int p = rem >> 6, ll = rem & 63;
            const int jr = ll & 15, g = ll >> 4;
            const int kg = kcw * 4 + g;
            const long grow = (long)(p << 10) + bj * 16 + jr;
            whP[i] = Wh + grow * (long)HID + kg * 8;
            wlP[i] = WL ? Wl + grow * (long)HID + kg * 8 : whP[i];
            wLds[i] = s * 8;
        }
    }

    f32x4 acc[P];
    #pragma unroll
    for (int i = 0; i < P; ++i) acc[i] = (f32x4)0.f;

    short8 rAh[2], rAl[2], rWh[2], rWl[2];
    auto LOADC = [&](int c) {
        const long ko = (long)c * 64;
        #pragma unroll
        for (int i = 0; i < 2; ++i) {
            rAh[i] = *(const short8*)(ahP[i] + ko);
            rAl[i] = *(const short8*)(alP[i] + ko);
        }
        if (doW) {
            #pragma unroll
            for (int i = 0; i < 2; ++i) {
                rWh[i] = *(const short8*)(whP[i] + ko);
                if (WL) rWl[i] = *(const short8*)(wlP[i] + ko);
            }
        }
    };
    auto STORE = [&](int c) {
        const int b = c & 1;
        #pragma unroll
        for (int i = 0; i < 2; ++i) {
            *(short8*)(Asm + b * ABUF + aLds[i]) = rAh[i];
            *(short8*)(Asm + b * ABUF + 4096 + aLds[i]) = rAl[i];
        }
        if (doW) {
            #pragma unroll
            for (int i = 0; i < 2; ++i) {
                *(short8*)(Wsm + b * WBUF + wLds[i]) = rWh[i];
                if (WL) *(short8*)(Wsm + b * WBUF + P * 1024 + wLds[i]) = rWl[i];
            }
        }
    };

    LOADC(0); STORE(0); LOADC(1);
    __syncthreads();

    for (int c = 0; c < NC; ++c) {
        const int b = c & 1;
        short8 fah[2], fal[2], fwh[2][P], fwl[2][P];
        #pragma unroll
        for (int kc = 0; kc < 2; ++kc) {
            const short* ab = Asm + b * ABUF + (kc * 256 + wv * 64 + l) * 8;
            fah[kc] = *(const short8*)ab;
            fal[kc] = *(const short8*)(ab + 4096);
            #pragma unroll
            for (int p = 0; p < P; ++p) {
                const short* wb = Wsm + b * WBUF + (kc * (P * 64) + p * 64 + l) * 8;
                fwh[kc][p] = *(const short8*)wb;
                if (WL) fwl[kc][p] = *(const short8*)(wb + P * 1024);
            }
        }
        if (c + 1 < NC) STORE(c + 1);
        if (c + 2 < NC) LOADC(c + 2);
        #pragma unroll
        for (int kc = 0; kc < 2; ++kc) {
            #pragma unroll
            for (int p = 0; p < P; ++p) {
                if constexpr (MODE == 0) {
                    TRI(fah[kc], fal[kc], fwh[kc][p], fwl[kc][p], acc[p]);
                } else {
                    MF(fal[kc], fwh[kc][p], acc[p]);
                    MF(fah[kc], fwh[kc][p], acc[p]);
                }
            }
        }
        __syncthreads();
    }

    const int jc = bj * 16 + r16;
    #pragma unroll
    for (int reg = 0; reg < 4; ++reg) {
        const long R = (long)bm * 64 + wv * 16 + gl * 4 + reg;
        if constexpr (MODE != 3) {
            #pragma unroll
            for (int p = 0; p < P; ++p)
                outf[R * H3 + p * HID + jc] = acc[p][reg] + bias[p * HID + jc];
        } else {
            const float* orow = gif + R * H3;
            const float rr = sigf(orow[jc] + acc[0][reg] + bias[jc]);
            const float zz = sigf(orow[HID + jc] + acc[1][reg] + bias[HID + jc]);
            const float nn = tanhf(orow[2 * HID + jc] + rr * (acc[2][reg] + bias[2 * HID + jc]));
            const float h = (1.f - zz) * nn + zz * hprev[R * HID + jc];
            outf[R * HID + jc] = h;
            if (outf2) outf2[R * HID + jc] = h;
            const unsigned short hb = f2bf(h), lb = f2bf(h - bf2f(hb));
            outh[R * HID + jc] = (short)hb;
            outl[R * HID + jc] = (short)lb;
        }
    }
}

// ============== 4-role pipelined step kernel (512 blocks, XCD-pinned) ==============
// Phase ph: role0 -> h0_ph ; role1 -> gi1_{ph-1} ; role2 -> h1_{ph-2} ;
// role3 -> gi0_{ph+2} (look-ahead, DUO wih0h).
struct StepP {
    const short* hih; const short* hil;
    const float* h_in;
    const short* eqh; const short* eql;
    float* gi0; float* gi1;
    const short* whh0h; const short* wih0h;
    const short* wih1h; const short* wih1l; const short* whh1h;
    const float* b_ih0; const float* b_hh0; const float* b_ih1; const float* b_hh1;
    float* h0f; float* h1f;
    short* h0ah; short* h0al; short* h1ah; short* h1al;
    float* hf0dst; float* hf1dst;     // d_out final-state tail
};

__global__ __launch_bounds__(256) void step_k(int ph, StepP P)
{
    const int id = blockIdx.x;
    const int xcd = id & 7, sub = (id >> 3) & 7, top = id >> 6;
    const int role = top >> 1, bm = top & 1;
    const int bj = xcd * 8 + sub;

    if (role == 0) {
        const int t = ph;
        if (t >= T_STEPS) return;
        const short* a1h = t ? P.h0ah + (size_t)(t - 1) * BH : P.hih;
        const short* a1l = t ? P.h0al + (size_t)(t - 1) * BH : P.hil;
        gru_core<3>(bm, bj, a1h, a1l, P.whh0h, nullptr, P.b_hh0,
                    P.gi0 + (size_t)t * BATCH * H3,
                    t ? P.h0f + (size_t)((t - 1) & 1) * BH : P.h_in,
                    P.h0f + (size_t)(t & 1) * BH,
                    P.h0ah + (size_t)t * BH, P.h0al + (size_t)t * BH,
                    (t == T_STEPS - 1) ? P.hf0dst : nullptr);
    } else if (role == 1) {
        const int s = ph - 1;
        if (s < 0 || s >= T_STEPS) return;
        gru_core<0>(bm, bj,
                    P.h0ah + (size_t)s * BH, P.h0al + (size_t)s * BH,
                    P.wih1h, P.wih1l, P.b_ih1,
                    nullptr, nullptr,
                    P.gi1 + (size_t)(s & 1) * BATCH * H3,
                    nullptr, nullptr, nullptr);
    } else if (role == 2) {
        const int s = ph - 2;
        if (s < 0 || s >= T_STEPS) return;
        const short* a1h = s ? P.h1ah + (size_t)(s - 1) * BH : P.hih + BH;
        const short* a1l = s ? P.h1al + (size_t)(s - 1) * BH : P.hil + BH;
        gru_core<3>(bm, bj, a1h, a1l, P.whh1h, nullptr, P.b_hh1,
                    P.gi1 + (size_t)(s & 1) * BATCH * H3,
                    s ? P.h1f + (size_t)((s - 1) & 1) * BH : P.h_in + BH,
                    P.h1f + (size_t)(s & 1) * BH,
                    P.h1ah + (size_t)s * BH, P.h1al + (size_t)s * BH,
                    (s == T_STEPS - 1) ? P.hf1dst : nullptr);
    } else {
        const int u = ph + 2;
        if (u >= T_STEPS) return;
        gru_core<1>(bm, bj,
                    P.eqh + (size_t)u * BH, P.eql + (size_t)u * BH,
                    P.wih0h, nullptr, P.b_ih0,
                    nullptr, nullptr,
                    P.gi0 + (size_t)u * BATCH * H3,
                    nullptr, nullptr, nullptr);
    }
}

// prologue: gi0 for steps 0..1 (256 blocks: t=id>>7, bm=(id>>6)&1, bj=id&63)
__global__ __launch_bounds__(256) void step_pre_k(StepP P)
{
    const int id = blockIdx.x;
    const int t = id >> 7, bm = (id >> 6) & 1, bj = id & 63;
    gru_core<1>(bm, bj,
                P.eqh + (size_t)t * BH, P.eql + (size_t)t * BH,
                P.wih0h, nullptr, P.b_ih0,
                nullptr, nullptr,
                P.gi0 + (size_t)t * BATCH * H3,
                nullptr, nullptr, nullptr);
}

// ============== batched attention scores + softmax (per b) ==============
__global__ __launch_bounds__(256) void scores_k(
    const short* __restrict__ Qh, const short* __restrict__ Ql,
    const short* __restrict__ Hh, const short* __restrict__ Hl,
    float* __restrict__ Pall)
{
    extern __shared__ short sm[];
    short* Asm = sm;
    short* Wsm = sm + 8192;
    const int b = blockIdx.x, tid = threadIdx.x;
    const int wv = tid >> 6, l = tid & 63;
    const int gl = l >> 4, cc = l & 15;

    const int arow = ((tid >> 6) & 3) * 16 + (tid & 15);
    const int ag   = (tid >> 4) & 3;
    const short* qhp = Qh + ((long)arow * BATCH + b) * HID + ag * 8;
    const short* qlp = Ql + ((long)arow * BATCH + b) * HID + ag * 8;
    const int aLds = tid * 8;

    const short *whp[2], *wlp[2]; int wLds[2];
    #pragma unroll
    for (int i = 0; i < 2; ++i) {
        const int s = tid + i * 256;
        const int srow = ((s >> 6) & 7) * 16 + (s & 15);
        const int sg   = (s >> 4) & 3;
        whp[i] = Hh + ((long)srow * BATCH + b) * HID + sg * 8;
        wlp[i] = Hl + ((long)srow * BATCH + b) * HID + sg * 8;
        wLds[i] = s * 8;
    }

    f32x4 acc[8];
    #pragma unroll
    for (int i = 0; i < 8; ++i) acc[i] = (f32x4)0.f;

    short8 rAh, rAl, rWh[2], rWl[2];
    auto LOADC = [&](int c) {
        rAh = *(const short8*)(qhp + c * 32);
        rAl = *(const short8*)(qlp + c * 32);
        #pragma unroll
        for (int i = 0; i < 2; ++i) {
            rWh[i] = *(const short8*)(whp[i] + c * 32);
            rWl[i] = *(const short8*)(wlp[i] + c * 32);
        }
    };
    auto STORE = [&](int c) {
        const int bb = c & 1;
        *(short8*)(Asm + bb * 4096 + aLds) = rAh;
        *(short8*)(Asm + bb * 4096 + 2048 + aLds) = rAl;
        #pragma unroll
        for (int i = 0; i < 2; ++i) {
            *(short8*)(Wsm + bb * 8192 + wLds[i]) = rWh[i];
            *(short8*)(Wsm + bb * 8192 + 4096 + wLds[i]) = rWl[i];
        }
    };

    LOADC(0); STORE(0); LOADC(1);
    __syncthreads();
    for (int c = 0; c < 32; ++c) {
        const int bb = c & 1;
        const short* abp = Asm + bb * 4096 + (wv * 64 + l) * 8;
        short8 ah = *(const short8*)abp;
        short8 al = *(const short8*)(abp + 2048);
        if (c + 1 < 32) STORE(c + 1);
        if (c + 2 < 32) LOADC(c + 2);
        #pragma unroll
        for (int jt = 0; jt < 8; ++jt) {
            const short* wbp = Wsm + bb * 8192 + (jt * 64 + l) * 8;
            short8 wh = *(const short8*)wbp;
            short8 wl = *(const short8*)(wbp + 4096);
            TRI(ah, al, wh, wl, acc[jt]);
        }
        __syncthreads();
    }

    #pragma unroll
    for (int reg = 0; reg < 4; ++reg) {
        float m = acc[0][reg];
        #pragma unroll
        for (int jt = 1; jt < 8; ++jt) m = fmaxf(m, acc[jt][reg]);
        #pragma unroll
        for (int off = 1; off < 16; off <<= 1) m = fmaxf(m, __shfl_xor(m, off));
        float e[8], ssum = 0.f;
        #pragma unroll
        for (int jt = 0; jt < 8; ++jt) { e[jt] = __expf(acc[jt][reg] - m); ssum += e[jt]; }
        #pragma unroll
        for (int off = 1; off < 16; off <<= 1) ssum += __shfl_xor(ssum, off);
        const float inv = 1.f / ssum;
        const int t = wv * 16 + gl * 4 + reg;
        #pragma unroll
        for (int jt = 0; jt < 8; ++jt)
            Pall[((long)t * BATCH + b) * SLEN + jt * 16 + cc] = e[jt] * inv;
    }
}

__global__ __launch_bounds__(256) void ctx_k(
    const float* __restrict__ Pall, const float* __restrict__ H,
    short* __restrict__ Ch, short* __restrict__ Cl)
{
    __shared__ float Ps[T_STEPS * SLEN];
    const int b = blockIdx.x, ht = blockIdx.y, tid = threadIdx.x;
    for (int i = 0; i < 32; ++i) {
        const int idx = i * 256 + tid;
        const int t = idx >> 7, s = idx & 127;
        Ps[idx] = Pall[((long)t * BATCH + b) * SLEN + s];
    }
    __syncthreads();
    const int col = ht * 256 + tid;
    for (int tg = 0; tg < 4; ++tg) {
        float a[16];
        #pragma unroll
        for (int j = 0; j < 16; ++j) a[j] = 0.f;
        for (int s = 0; s < SLEN; ++s) {
            const float hv = H[((long)s * BATCH + b) * HID + col];
            #pragma unroll
            for (int j = 0; j < 16; ++j)
                a[j] = fmaf(Ps[(tg * 16 + j) * SLEN + s], hv, a[j]);
        }
        #pragma unroll
        for (int j = 0; j < 16; ++j) {
            const long row = (long)(tg * 16 + j) * BATCH + b;
            const unsigned short hi = f2bf(a[j]);
            const unsigned short lo = f2bf(a[j] - bf2f(hi));
            Ch[row * HID + col] = (short)hi;
            Cl[row * HID + col] = (short)lo;
        }
    }
}

// =========================== launch ===========================
extern "C" void kernel_launch(void* const* d_in, const int* in_sizes, int n_in,
                              void* d_out, int out_size, void* d_ws, size_t ws_size,
                              hipStream_t stream)
{
    const int*   input = (const int*)  d_in[0];
    const float* h_in  = (const float*)d_in[1];
    const float* Hbuf  = (const float*)d_in[2];
    const float* emb   = (const float*)d_in[3];
    const float* w_ih  = (const float*)d_in[4];
    const float* w_hh  = (const float*)d_in[5];
    const float* b_ih  = (const float*)d_in[6];
    const float* b_hh  = (const float*)d_in[7];
    const float* L1    = (const float*)d_in[8];
    const float* L2    = (const float*)d_in[9];

    float* out = (float*)d_out;

    char* basep = (char*)d_ws;
    size_t off = 0;
    auto alloc = [&](size_t bytes) -> char* {
        off = (off + 255) & ~(size_t)255;
        char* p = basep + off; off += bytes; return p;
    };
    short* wih0h = (short*)alloc(3072L*1024*2);
    short* whh0h = (short*)alloc(3072L*1024*2);
    short* wih1h = (short*)alloc(3072L*1024*2); short* wih1l = (short*)alloc(3072L*1024*2);
    short* whh1h = (short*)alloc(3072L*1024*2);
    short* l1h   = (short*)alloc(1024L*1024*2); short* l1l   = (short*)alloc(1024L*1024*2);
    short* l2h   = (short*)alloc(1024L*2048*2); short* l2l   = (short*)alloc(1024L*2048*2);
    short* Hh    = (short*)alloc(16777216L*2);  short* Hl    = (short*)alloc(16777216L*2);
    short* hih   = (short*)alloc(262144L*2);    short* hil   = (short*)alloc(262144L*2);
    short* h0ah  = (short*)alloc(8388608L*2);   short* h0al  = (short*)alloc(8388608L*2);
    short* h1ah  = (short*)alloc(8388608L*2);   short* h1al  = (short*)alloc(8388608L*2);
    short* eqh   = (short*)alloc(8388608L*2);   short* eql   = (short*)alloc(8388608L*2);
    float* gi0   = (float*)alloc(25165824L*4);
    float* gi1   = (float*)alloc(2L*BATCH*H3*4);
    float* h0f   = (float*)alloc(524288L*4);
    float* h1f   = (float*)alloc(524288L*4);
    float* Pall  = (float*)alloc(1048576L*4);
    short* ctxh  = (short*)gi0;                 // gi0 dead after step loop
    short* ctxl  = ctxh + 8388608L;

    const dim3 blk(256);
    const size_t SMB = 32768 * sizeof(short);                      // 65536
    const size_t SM3 = (2 * 8192 + 2 * 3 * 2048) * sizeof(short);  // 57344

    // ---- phase 0: plane conversions (fused) ----
    conv_w3_k<<<4608, blk, 0, stream>>>(w_ih, wih0h,
                                        w_hh, whh0h,
                                        w_hh + 3145728L, whh1h);
    conv_planes_k<true ><<<1536, blk, 0, stream>>>(w_ih + 3145728L, wih1h, wih1l);
    conv_l12_k<<<1536, blk, 0, stream>>>(L1, l1h, l1l, L2, l2h, l2l);
    conv_planes_k<true ><<<8192, blk, 0, stream>>>(Hbuf, Hh, Hl);
    conv_planes_k<true ><<<128,  blk, 0, stream>>>(h_in, hih, hil);
    conv_gather_k<<<4096, blk, 0, stream>>>(emb, input, eqh, eql);

    // ---- 4-role pipelined recurrence ----
    StepP sp;
    sp.hih = hih; sp.hil = hil; sp.h_in = h_in;
    sp.eqh = eqh; sp.eql = eql;
    sp.gi0 = gi0; sp.gi1 = gi1;
    sp.whh0h = whh0h; sp.wih0h = wih0h;
    sp.wih1h = wih1h; sp.wih1l = wih1l; sp.whh1h = whh1h;
    sp.b_ih0 = b_ih; sp.b_hh0 = b_hh;
    sp.b_ih1 = b_ih + H3; sp.b_hh1 = b_hh + H3;
    sp.h0f = h0f; sp.h1f = h1f;
    sp.h0ah = h0ah; sp.h0al = h0al; sp.h1ah = h1ah; sp.h1al = h1al;
    sp.hf0dst = out + (long)T_STEPS * BH;
    sp.hf1dst = out + (long)T_STEPS * BH + BH;

    step_pre_k<<<dim3(256), blk, SM3, stream>>>(sp);    // gi0[0..1]
    for (int ph = 0; ph <= T_STEPS + 1; ++ph)
        step_k<<<dim3(512), blk, SM3, stream>>>(ph, sp);

    // ---- batched attention + output ----
    gemm_big<1, false, false><<<dim3(512), blk, SMB, stream>>>(
        h1ah, h1al, nullptr, nullptr, l1h, l1l, 1024, 8,
        nullptr, nullptr, eqh, eql, HID);
    scores_k<<<dim3(BATCH), blk, 49152, stream>>>(eqh, eql, Hh, Hl, Pall);
    ctx_k<<<dim3(BATCH, 4), blk, 0, stream>>>(Pall, Hbuf, ctxh, ctxl);
    gemm_big<2, true, false><<<dim3(512), blk, SMB, stream>>>(
        ctxh, ctxl, h1ah, h1al, l2h, l2l, 2048, 8,
        nullptr, out, nullptr, nullptr, HID);
}